// Round 4
// baseline (1379.248 us; speedup 1.0000x reference)
//
#include <hip/hip_runtime.h>

// SAGEConv mean aggregator — bucketed LDS-accumulation version.
// R3 post-mortem: k_fill was 121us with 105MB WRITE_SIZE for a 6.4MB array
// (64B-line amplification on random 4B writes + global atomic-rtn latency
// chain). R4: partition edges into 64-node dst-buckets (LDS-rank scatter),
// then aggregate each bucket in 32KB of LDS fp32 accumulators via ds_add_f32
// (conflict-free even/odd split). CSR (count/scan/fill/pull) deleted.
// Phases: cvt_h, cvt_w, bhist, bscan, part, agg(mean,bf16), mfma-gemm.

constexpr int NN = 100000;
constexpr int NE = 1600000;
constexpr int D  = 128;
constexpr int BK = 64;                      // nodes per bucket
constexpr int NB = (NN + BK - 1) / BK;      // 1563 buckets
constexpr int PB = 4096;                    // edges per partition block

typedef __attribute__((ext_vector_type(8))) short short8;   // 8 bf16 (4 VGPR)
typedef __attribute__((ext_vector_type(4))) float floatx4;  // MFMA C/D

static __device__ __forceinline__ unsigned short f2bf(float f) {
    unsigned u = __float_as_uint(f);
    unsigned r = ((u >> 16) & 1u) + 0x7fffu;
    return (unsigned short)((u + r) >> 16);
}
static __device__ __forceinline__ float bflo(unsigned u) { return __uint_as_float(u << 16); }
static __device__ __forceinline__ float bfhi(unsigned u) { return __uint_as_float(u & 0xffff0000u); }

// ---------------------------------------------------------------------------
// h (fp32, NN x 128) -> hb (bf16). 8 elems/thread, 16B stores.
// ---------------------------------------------------------------------------
__global__ __launch_bounds__(256) void k_cvt_h(
    const float* __restrict__ h, unsigned short* __restrict__ hb)
{
    int i = blockIdx.x * 256 + threadIdx.x;          // NN*D/8 = 1.6M, exact
    const float4* h4 = (const float4*)h;
    float4 a = h4[(size_t)i * 2];
    float4 b = h4[(size_t)i * 2 + 1];
    uint4 o;
    o.x = (unsigned)f2bf(a.x) | ((unsigned)f2bf(a.y) << 16);
    o.y = (unsigned)f2bf(a.z) | ((unsigned)f2bf(a.w) << 16);
    o.z = (unsigned)f2bf(b.x) | ((unsigned)f2bf(b.y) << 16);
    o.w = (unsigned)f2bf(b.z) | ((unsigned)f2bf(b.w) << 16);
    ((uint4*)hb)[i] = o;
}

// ---------------------------------------------------------------------------
// Pack Wcat = [W_self ; W_neigh] (256x128) into B-fragment order (bf16).
// ---------------------------------------------------------------------------
__global__ __launch_bounds__(128) void k_cvt_w(
    const float* __restrict__ Wself, const float* __restrict__ Wneigh,
    unsigned short* __restrict__ Wp)
{
    int kg  = blockIdx.x;        // 0..31
    int col = threadIdx.x;       // 0..127
    unsigned short v[8];
#pragma unroll
    for (int j = 0; j < 8; ++j) {
        int k = kg * 8 + j;
        const float* W = (k < 128) ? (Wself + (size_t)k * D)
                                   : (Wneigh + (size_t)(k - 128) * D);
        v[j] = f2bf(W[col]);
    }
    uint4 o;
    o.x = (unsigned)v[0] | ((unsigned)v[1] << 16);
    o.y = (unsigned)v[2] | ((unsigned)v[3] << 16);
    o.z = (unsigned)v[4] | ((unsigned)v[5] << 16);
    o.w = (unsigned)v[6] | ((unsigned)v[7] << 16);
    ((uint4*)Wp)[kg * 128 + col] = o;
}

// ---------------------------------------------------------------------------
// Bucket histogram (LDS-aggregated to cut global atomics).
// ---------------------------------------------------------------------------
__global__ __launch_bounds__(256) void k_bhist(
    const int* __restrict__ dst, int* __restrict__ bcnt)
{
    __shared__ int lh[NB];
    for (int i = threadIdx.x; i < NB; i += 256) lh[i] = 0;
    __syncthreads();
    for (int e = blockIdx.x * 256 + threadIdx.x; e < NE; e += 512 * 256)
        atomicAdd(&lh[dst[e] >> 6], 1);
    __syncthreads();
    for (int i = threadIdx.x; i < NB; i += 256)
        if (lh[i]) atomicAdd(&bcnt[i], lh[i]);
}

// ---------------------------------------------------------------------------
// Exclusive scan of NB bucket counts (single block, 256 thr x 7).
// Writes bbase[0..NB] (bbase[NB]=NE) and initializes bcursor.
// ---------------------------------------------------------------------------
__global__ __launch_bounds__(256) void k_bscan(
    const int* __restrict__ bcnt, int* __restrict__ bbase,
    int* __restrict__ bcursor)
{
    __shared__ int sd[256];
    const int t = threadIdx.x;
    const int base = t * 7;
    int c[7];
    int local = 0;
#pragma unroll
    for (int j = 0; j < 7; ++j) {
        int idx = base + j;
        c[j] = (idx < NB) ? bcnt[idx] : 0;
        local += c[j];
    }
    sd[t] = local;
    __syncthreads();
    for (int off = 1; off < 256; off <<= 1) {
        int v = (t >= off) ? sd[t - off] : 0;
        __syncthreads();
        sd[t] += v;
        __syncthreads();
    }
    int run = sd[t] - local;
#pragma unroll
    for (int j = 0; j < 7; ++j) {
        int idx = base + j;
        if (idx < NB) { bbase[idx] = run; bcursor[idx] = run; }
        run += c[j];
    }
    if (t == 255) bbase[NB] = run;   // == NE
}

// ---------------------------------------------------------------------------
// Partition edges into bucket-contiguous packed[] = src | (dst&63)<<17.
// Per-edge rank via LDS cursor (no global atomic-return latency chain);
// one global reserve atomic per (block, nonempty bucket).
// ---------------------------------------------------------------------------
__global__ __launch_bounds__(256) void k_part(
    const int* __restrict__ src, const int* __restrict__ dst,
    int* __restrict__ bcursor, unsigned* __restrict__ packed)
{
    __shared__ int lh[NB];
    const int t = threadIdx.x;
    const int e0 = blockIdx.x * PB;

    for (int i = t; i < NB; i += 256) lh[i] = 0;
    __syncthreads();

    int myd[16];
#pragma unroll
    for (int j = 0; j < 16; ++j) {
        int e = e0 + j * 256 + t;
        myd[j] = (e < NE) ? dst[e] : -1;
        if (myd[j] >= 0) atomicAdd(&lh[myd[j] >> 6], 1);
    }
    __syncthreads();
    // reserve global ranges; lh becomes the running global cursor
    for (int i = t; i < NB; i += 256) {
        int c = lh[i];
        if (c) lh[i] = atomicAdd(&bcursor[i], c);
    }
    __syncthreads();
#pragma unroll
    for (int j = 0; j < 16; ++j) {
        int e = e0 + j * 256 + t;
        if (myd[j] >= 0) {
            int b = myd[j] >> 6;
            int pos = atomicAdd(&lh[b], 1);
            packed[pos] = (unsigned)src[e] | ((unsigned)(myd[j] & 63) << 17);
        }
    }
}

// ---------------------------------------------------------------------------
// Bucket aggregation: one block per bucket (64 nodes). 32KB LDS fp32
// accumulators, even cols at node*128+p, odd cols at node*128+64+p so the
// per-edge ds_add pattern is 2-way-max bank aliasing (free). Each edge:
// one coalesced 256B row gather (uint per lane) + 2 ds_add_f32 per lane.
// Writes the mean in bf16 to nb.
// ---------------------------------------------------------------------------
__global__ __launch_bounds__(256) void k_agg(
    const unsigned short* __restrict__ hb, const int* __restrict__ bbase,
    const unsigned* __restrict__ packed, unsigned short* __restrict__ nb)
{
    __shared__ float acc[BK * 128];    // 32 KiB
    __shared__ int degl[BK];

    const int t    = threadIdx.x;
    const int wave = t >> 6;
    const int lane = t & 63;
    const int b    = blockIdx.x;

    for (int i = t; i < BK * 128; i += 256) acc[i] = 0.0f;
    if (t < BK) degl[t] = 0;
    __syncthreads();

    const int ebeg = bbase[b];
    const int eend = bbase[b + 1];
    const unsigned* __restrict__ hrow = (const unsigned*)hb;   // 64 uints/row

    int e0 = ebeg + wave * 8;
    unsigned pk = (e0 < eend) ? packed[min(e0 + (lane & 7), eend - 1)] : 0u;
    for (; e0 < eend; e0 += 32) {
        int nxt = e0 + 32;
        unsigned pknext = (nxt < eend) ? packed[min(nxt + (lane & 7), eend - 1)] : 0u;
        int n = min(8, eend - e0);
        if (n == 8) {
#pragma unroll
            for (int j = 0; j < 8; ++j) {
                unsigned sp = (unsigned)__builtin_amdgcn_readlane((int)pk, j);
                int s  = (int)(sp & 0x1FFFFu);
                int dl = (int)((sp >> 17) & 63u);
                unsigned u = hrow[(size_t)s * 64 + lane];
                atomicAdd(&acc[dl * 128 + lane],      bflo(u));
                atomicAdd(&acc[dl * 128 + 64 + lane], bfhi(u));
                if (lane == 0) atomicAdd(&degl[dl], 1);
            }
        } else {
            for (int j = 0; j < n; ++j) {
                unsigned sp = (unsigned)__builtin_amdgcn_readlane((int)pk, j);
                int s  = (int)(sp & 0x1FFFFu);
                int dl = (int)((sp >> 17) & 63u);
                unsigned u = hrow[(size_t)s * 64 + lane];
                atomicAdd(&acc[dl * 128 + lane],      bflo(u));
                atomicAdd(&acc[dl * 128 + 64 + lane], bfhi(u));
                if (lane == 0) atomicAdd(&degl[dl], 1);
            }
        }
        pk = pknext;
    }
    __syncthreads();

    const int nodes = min(BK, NN - b * BK);
    for (int u = t; u < nodes * 64; u += 256) {
        int node = u >> 6, p = u & 63;
        float inv = 1.0f / (float)max(degl[node], 1);
        float lo = acc[node * 128 + p] * inv;
        float hi = acc[node * 128 + 64 + p] * inv;
        ((unsigned*)nb)[(size_t)(b * BK + node) * 64 + p] =
            (unsigned)f2bf(lo) | ((unsigned)f2bf(hi) << 16);
    }
}

// ---------------------------------------------------------------------------
// out = [hb | nb] @ Wcat via v_mfma_f32_16x16x32_bf16 (unchanged from R3).
// ---------------------------------------------------------------------------
__global__ __launch_bounds__(256) void k_gemm(
    const unsigned short* __restrict__ hb, const unsigned short* __restrict__ nb,
    const unsigned short* __restrict__ Wp, float* __restrict__ out)
{
    __shared__ unsigned short Wl[128 * 128];   // 32 KiB

    const int t    = threadIdx.x;
    const int wave = t >> 6;
    const int lane = t & 63;
    const int l16  = lane & 15;
    const int kg4  = lane >> 4;          // 0..3
    const int v0   = blockIdx.x * 128;

    floatx4 acc[2][8];
#pragma unroll
    for (int rt = 0; rt < 2; ++rt)
#pragma unroll
        for (int ct = 0; ct < 8; ++ct)
            acc[rt][ct] = (floatx4){0.f, 0.f, 0.f, 0.f};

    int rowg[2];
#pragma unroll
    for (int rt = 0; rt < 2; ++rt) {
        int row = v0 + wave * 32 + rt * 16 + l16;
        rowg[rt] = (row < NN) ? row : (NN - 1);   // clamp; stores guarded
    }

    for (int half = 0; half < 2; ++half) {
        __syncthreads();
#pragma unroll
        for (int i = 0; i < 8; ++i) {
            int u = t + i * 256;
            ((uint4*)Wl)[u] = ((const uint4*)Wp)[half * 2048 + u];
        }
        __syncthreads();

        const unsigned short* __restrict__ Xsrc = (half == 0) ? hb : nb;
#pragma unroll
        for (int ks = 0; ks < 4; ++ks) {
            short8 a[2];
#pragma unroll
            for (int rt = 0; rt < 2; ++rt)
                a[rt] = *(const short8*)(Xsrc + (size_t)rowg[rt] * D + ks * 32 + kg4 * 8);
#pragma unroll
            for (int ct = 0; ct < 8; ++ct) {
                const short8 bfrag = *(const short8*)(Wl + (((ks * 4 + kg4) * 128) + ct * 16 + l16) * 8);
                acc[0][ct] = __builtin_amdgcn_mfma_f32_16x16x32_bf16(a[0], bfrag, acc[0][ct], 0, 0, 0);
                acc[1][ct] = __builtin_amdgcn_mfma_f32_16x16x32_bf16(a[1], bfrag, acc[1][ct], 0, 0, 0);
            }
        }
    }

    // C/D layout: col = lane&15, row = (lane>>4)*4 + reg
#pragma unroll
    for (int rt = 0; rt < 2; ++rt) {
        int rbase = v0 + wave * 32 + rt * 16 + kg4 * 4;
#pragma unroll
        for (int r = 0; r < 4; ++r) {
            int row = rbase + r;
            if (row < NN) {
                float* o = out + (size_t)row * D + l16;
#pragma unroll
                for (int ct = 0; ct < 8; ++ct)
                    o[ct * 16] = acc[rt][ct][r];
            }
        }
    }
}

extern "C" void kernel_launch(void* const* d_in, const int* in_sizes, int n_in,
                              void* d_out, int out_size, void* d_ws, size_t ws_size,
                              hipStream_t stream) {
    const float* h      = (const float*)d_in[0];
    const int*   src    = (const int*)d_in[1];
    const int*   dst    = (const int*)d_in[2];
    const float* Wself  = (const float*)d_in[3];
    const float* Wneigh = (const float*)d_in[4];
    float*       out    = (float*)d_out;

    // workspace layout (~58 MB)
    unsigned short* hb = (unsigned short*)d_ws;            // NN*D bf16 (25.6MB)
    unsigned short* nb = hb + (size_t)NN * D;              // NN*D bf16 (25.6MB)
    unsigned short* Wp = nb + (size_t)NN * D;              // 256*128 bf16 (64KB)
    unsigned* packed   = (unsigned*)(Wp + 256 * D);        // NE (6.4MB)
    int* bcnt          = (int*)(packed + NE);              // NB
    int* bbase         = bcnt + NB;                        // NB+1
    int* bcursor       = bbase + NB + 1;                   // NB

    hipMemsetAsync(bcnt, 0, NB * sizeof(int), stream);

    k_cvt_h <<<dim3(NN * D / 8 / 256), 256, 0, stream>>>(h, hb);
    k_cvt_w <<<dim3(32), 128, 0, stream>>>(Wself, Wneigh, Wp);
    k_bhist <<<dim3(512), 256, 0, stream>>>(dst, bcnt);
    k_bscan <<<dim3(1), 256, 0, stream>>>(bcnt, bbase, bcursor);
    k_part  <<<dim3((NE + PB - 1) / PB), 256, 0, stream>>>(src, dst, bcursor, packed);
    k_agg   <<<dim3(NB), 256, 0, stream>>>(hb, bbase, packed, nb);
    k_gemm  <<<dim3((NN + 127) / 128), 256, 0, stream>>>(hb, nb, Wp, out);
}

// Round 5
// 262.560 us; speedup vs baseline: 5.2531x; 5.2531x over previous
//
#include <hip/hip_runtime.h>

// SAGEConv mean aggregator — bucket partition + in-LDS counting sort +
// register-accumulator pull.
// R4 post-mortem: LDS-atomic push aggregation serialized (compiler can't
// reorder gathers across atomics -> ~450cyc exposed latency per edge,
// 1190us, VALUBusy 3%). R5: per-bucket counting sort of src into LDS,
// then k_pull-style register accumulation (no atomics in hot loop).
// R3's k_fill lesson kept: no scattered 4B global writes anywhere.
// Phases: cvt_h, cvt_w, bhist, bscan, part, agg(sort+pull+mean), mfma-gemm.

constexpr int NN = 100000;
constexpr int NE = 1600000;
constexpr int D  = 128;
constexpr int BK = 64;                      // nodes per bucket
constexpr int NB = (NN + BK - 1) / BK;      // 1563 buckets
constexpr int PB = 4096;                    // edges per partition block
constexpr int CAP = 4096;                   // max edges/bucket (mean 1024, +96 sigma)

typedef __attribute__((ext_vector_type(8))) short short8;   // 8 bf16 (4 VGPR)
typedef __attribute__((ext_vector_type(4))) float floatx4;  // MFMA C/D

static __device__ __forceinline__ unsigned short f2bf(float f) {
    unsigned u = __float_as_uint(f);
    unsigned r = ((u >> 16) & 1u) + 0x7fffu;
    return (unsigned short)((u + r) >> 16);
}
static __device__ __forceinline__ float bflo(unsigned u) { return __uint_as_float(u << 16); }
static __device__ __forceinline__ float bfhi(unsigned u) { return __uint_as_float(u & 0xffff0000u); }

// ---------------------------------------------------------------------------
// h (fp32, NN x 128) -> hb (bf16). 8 elems/thread, 16B stores.
// ---------------------------------------------------------------------------
__global__ __launch_bounds__(256) void k_cvt_h(
    const float* __restrict__ h, unsigned short* __restrict__ hb)
{
    int i = blockIdx.x * 256 + threadIdx.x;          // NN*D/8 = 1.6M, exact
    const float4* h4 = (const float4*)h;
    float4 a = h4[(size_t)i * 2];
    float4 b = h4[(size_t)i * 2 + 1];
    uint4 o;
    o.x = (unsigned)f2bf(a.x) | ((unsigned)f2bf(a.y) << 16);
    o.y = (unsigned)f2bf(a.z) | ((unsigned)f2bf(a.w) << 16);
    o.z = (unsigned)f2bf(b.x) | ((unsigned)f2bf(b.y) << 16);
    o.w = (unsigned)f2bf(b.z) | ((unsigned)f2bf(b.w) << 16);
    ((uint4*)hb)[i] = o;
}

// ---------------------------------------------------------------------------
// Pack Wcat = [W_self ; W_neigh] (256x128) into B-fragment order (bf16).
// ---------------------------------------------------------------------------
__global__ __launch_bounds__(128) void k_cvt_w(
    const float* __restrict__ Wself, const float* __restrict__ Wneigh,
    unsigned short* __restrict__ Wp)
{
    int kg  = blockIdx.x;        // 0..31
    int col = threadIdx.x;       // 0..127
    unsigned short v[8];
#pragma unroll
    for (int j = 0; j < 8; ++j) {
        int k = kg * 8 + j;
        const float* W = (k < 128) ? (Wself + (size_t)k * D)
                                   : (Wneigh + (size_t)(k - 128) * D);
        v[j] = f2bf(W[col]);
    }
    uint4 o;
    o.x = (unsigned)v[0] | ((unsigned)v[1] << 16);
    o.y = (unsigned)v[2] | ((unsigned)v[3] << 16);
    o.z = (unsigned)v[4] | ((unsigned)v[5] << 16);
    o.w = (unsigned)v[6] | ((unsigned)v[7] << 16);
    ((uint4*)Wp)[kg * 128 + col] = o;
}

// ---------------------------------------------------------------------------
// Bucket histogram (LDS-aggregated; 128 blocks -> 128*NB flush atomics).
// ---------------------------------------------------------------------------
__global__ __launch_bounds__(256) void k_bhist(
    const int* __restrict__ dst, int* __restrict__ bcnt)
{
    __shared__ int lh[NB];
    for (int i = threadIdx.x; i < NB; i += 256) lh[i] = 0;
    __syncthreads();
    for (int e = blockIdx.x * 256 + threadIdx.x; e < NE; e += 128 * 256)
        atomicAdd(&lh[dst[e] >> 6], 1);
    __syncthreads();
    for (int i = threadIdx.x; i < NB; i += 256)
        if (lh[i]) atomicAdd(&bcnt[i], lh[i]);
}

// ---------------------------------------------------------------------------
// Exclusive scan of NB bucket counts; writes bbase[0..NB], inits bcursor.
// ---------------------------------------------------------------------------
__global__ __launch_bounds__(256) void k_bscan(
    const int* __restrict__ bcnt, int* __restrict__ bbase,
    int* __restrict__ bcursor)
{
    __shared__ int sd[256];
    const int t = threadIdx.x;
    const int base = t * 7;
    int c[7];
    int local = 0;
#pragma unroll
    for (int j = 0; j < 7; ++j) {
        int idx = base + j;
        c[j] = (idx < NB) ? bcnt[idx] : 0;
        local += c[j];
    }
    sd[t] = local;
    __syncthreads();
    for (int off = 1; off < 256; off <<= 1) {
        int v = (t >= off) ? sd[t - off] : 0;
        __syncthreads();
        sd[t] += v;
        __syncthreads();
    }
    int run = sd[t] - local;
#pragma unroll
    for (int j = 0; j < 7; ++j) {
        int idx = base + j;
        if (idx < NB) { bbase[idx] = run; bcursor[idx] = run; }
        run += c[j];
    }
    if (t == 255) bbase[NB] = run;   // == NE
}

// ---------------------------------------------------------------------------
// Partition edges into bucket-contiguous packed[] = src | (dst&63)<<17.
// LDS-rank within block; one global reserve atomic per (block, bucket);
// the packed writes per (block,bucket) are contiguous (1-2 lines).
// ---------------------------------------------------------------------------
__global__ __launch_bounds__(256) void k_part(
    const int* __restrict__ src, const int* __restrict__ dst,
    int* __restrict__ bcursor, unsigned* __restrict__ packed)
{
    __shared__ int lh[NB];
    const int t = threadIdx.x;
    const int e0 = blockIdx.x * PB;

    for (int i = t; i < NB; i += 256) lh[i] = 0;
    __syncthreads();

    int myd[16];
#pragma unroll
    for (int j = 0; j < 16; ++j) {
        int e = e0 + j * 256 + t;
        myd[j] = (e < NE) ? dst[e] : -1;
        if (myd[j] >= 0) atomicAdd(&lh[myd[j] >> 6], 1);
    }
    __syncthreads();
    for (int i = t; i < NB; i += 256) {
        int c = lh[i];
        if (c) lh[i] = atomicAdd(&bcursor[i], c);
    }
    __syncthreads();
#pragma unroll
    for (int j = 0; j < 16; ++j) {
        int e = e0 + j * 256 + t;
        if (myd[j] >= 0) {
            int b = myd[j] >> 6;
            int pos = atomicAdd(&lh[b], 1);
            packed[pos] = (unsigned)src[e] | ((unsigned)(myd[j] & 63) << 17);
        }
    }
}

// ---------------------------------------------------------------------------
// Per-bucket: counting-sort src into LDS (hist pass + scatter pass over the
// L2-hot packed range), then pull-style register accumulation: 16 lanes per
// node (uint4 = 256B row gather), 16 node-slots, 4 nodes per slot. No
// atomics in the gather loop -> loads pipeline freely. Mean written bf16.
// ---------------------------------------------------------------------------
__global__ __launch_bounds__(256) void k_agg(
    const unsigned short* __restrict__ hb, const int* __restrict__ bbase,
    const unsigned* __restrict__ packed, unsigned short* __restrict__ nb)
{
    __shared__ unsigned sorted[CAP];       // 16 KiB
    __shared__ int cnt[BK], offs[BK], cur[BK];

    const int t = threadIdx.x;
    const int b = blockIdx.x;
    const int ebeg = bbase[b];
    const int ecnt = min(bbase[b + 1] - ebeg, CAP);

    if (t < BK) cnt[t] = 0;
    __syncthreads();
    for (int i = t; i < ecnt; i += 256)
        atomicAdd(&cnt[packed[ebeg + i] >> 17], 1);
    __syncthreads();
    if (t < BK) {                       // wave 0: 64-wide shuffle scan
        int v = cnt[t];
        int sum = v;
#pragma unroll
        for (int off = 1; off < 64; off <<= 1) {
            int u = __shfl_up(sum, off, 64);
            if (t >= off) sum += u;
        }
        offs[t] = sum - v;
        cur[t]  = sum - v;
    }
    __syncthreads();
    for (int i = t; i < ecnt; i += 256) {
        unsigned pk = packed[ebeg + i];
        int pos = atomicAdd(&cur[pk >> 17], 1);
        sorted[pos] = pk & 0x1FFFFu;    // LDS scatter: cheap
    }
    __syncthreads();

    const int slot = t >> 4;            // 0..15
    const int l16  = t & 15;
    const uint4* __restrict__ h4 = (const uint4*)hb;   // 16 uint4 per row
    const int nodes = min(BK, NN - b * BK);

#pragma unroll
    for (int ni = 0; ni < 4; ++ni) {
        int node = slot + ni * 16;
        if (node >= nodes) continue;
        const int beg = offs[node];
        const int n   = cnt[node];
        float a0[8] = {0,0,0,0,0,0,0,0};
        float a1[8] = {0,0,0,0,0,0,0,0};
        int e = 0;
        for (; e + 1 < n; e += 2) {
            int s0 = (int)sorted[beg + e];
            int s1 = (int)sorted[beg + e + 1];
            uint4 x = h4[(size_t)s0 * 16 + l16];
            uint4 y = h4[(size_t)s1 * 16 + l16];
            a0[0] += bflo(x.x); a0[1] += bfhi(x.x);
            a0[2] += bflo(x.y); a0[3] += bfhi(x.y);
            a0[4] += bflo(x.z); a0[5] += bfhi(x.z);
            a0[6] += bflo(x.w); a0[7] += bfhi(x.w);
            a1[0] += bflo(y.x); a1[1] += bfhi(y.x);
            a1[2] += bflo(y.y); a1[3] += bfhi(y.y);
            a1[4] += bflo(y.z); a1[5] += bfhi(y.z);
            a1[6] += bflo(y.w); a1[7] += bfhi(y.w);
        }
        if (e < n) {
            uint4 x = h4[(size_t)sorted[beg + e] * 16 + l16];
            a0[0] += bflo(x.x); a0[1] += bfhi(x.x);
            a0[2] += bflo(x.y); a0[3] += bfhi(x.y);
            a0[4] += bflo(x.z); a0[5] += bfhi(x.z);
            a0[6] += bflo(x.w); a0[7] += bfhi(x.w);
        }
        float inv = (n > 0) ? 1.0f / (float)n : 0.0f;
        uint4 o;
        o.x = (unsigned)f2bf((a0[0]+a1[0])*inv) | ((unsigned)f2bf((a0[1]+a1[1])*inv) << 16);
        o.y = (unsigned)f2bf((a0[2]+a1[2])*inv) | ((unsigned)f2bf((a0[3]+a1[3])*inv) << 16);
        o.z = (unsigned)f2bf((a0[4]+a1[4])*inv) | ((unsigned)f2bf((a0[5]+a1[5])*inv) << 16);
        o.w = (unsigned)f2bf((a0[6]+a1[6])*inv) | ((unsigned)f2bf((a0[7]+a1[7])*inv) << 16);
        ((uint4*)nb)[(size_t)(b * BK + node) * 16 + l16] = o;
    }
}

// ---------------------------------------------------------------------------
// out = [hb | nb] @ Wcat via v_mfma_f32_16x16x32_bf16 (unchanged from R3).
// ---------------------------------------------------------------------------
__global__ __launch_bounds__(256) void k_gemm(
    const unsigned short* __restrict__ hb, const unsigned short* __restrict__ nb,
    const unsigned short* __restrict__ Wp, float* __restrict__ out)
{
    __shared__ unsigned short Wl[128 * 128];   // 32 KiB

    const int t    = threadIdx.x;
    const int wave = t >> 6;
    const int lane = t & 63;
    const int l16  = lane & 15;
    const int kg4  = lane >> 4;          // 0..3
    const int v0   = blockIdx.x * 128;

    floatx4 acc[2][8];
#pragma unroll
    for (int rt = 0; rt < 2; ++rt)
#pragma unroll
        for (int ct = 0; ct < 8; ++ct)
            acc[rt][ct] = (floatx4){0.f, 0.f, 0.f, 0.f};

    int rowg[2];
#pragma unroll
    for (int rt = 0; rt < 2; ++rt) {
        int row = v0 + wave * 32 + rt * 16 + l16;
        rowg[rt] = (row < NN) ? row : (NN - 1);   // clamp; stores guarded
    }

    for (int half = 0; half < 2; ++half) {
        __syncthreads();
#pragma unroll
        for (int i = 0; i < 8; ++i) {
            int u = t + i * 256;
            ((uint4*)Wl)[u] = ((const uint4*)Wp)[half * 2048 + u];
        }
        __syncthreads();

        const unsigned short* __restrict__ Xsrc = (half == 0) ? hb : nb;
#pragma unroll
        for (int ks = 0; ks < 4; ++ks) {
            short8 a[2];
#pragma unroll
            for (int rt = 0; rt < 2; ++rt)
                a[rt] = *(const short8*)(Xsrc + (size_t)rowg[rt] * D + ks * 32 + kg4 * 8);
#pragma unroll
            for (int ct = 0; ct < 8; ++ct) {
                const short8 bfrag = *(const short8*)(Wl + (((ks * 4 + kg4) * 128) + ct * 16 + l16) * 8);
                acc[0][ct] = __builtin_amdgcn_mfma_f32_16x16x32_bf16(a[0], bfrag, acc[0][ct], 0, 0, 0);
                acc[1][ct] = __builtin_amdgcn_mfma_f32_16x16x32_bf16(a[1], bfrag, acc[1][ct], 0, 0, 0);
            }
        }
    }

    // C/D layout: col = lane&15, row = (lane>>4)*4 + reg
#pragma unroll
    for (int rt = 0; rt < 2; ++rt) {
        int rbase = v0 + wave * 32 + rt * 16 + kg4 * 4;
#pragma unroll
        for (int r = 0; r < 4; ++r) {
            int row = rbase + r;
            if (row < NN) {
                float* o = out + (size_t)row * D + l16;
#pragma unroll
                for (int ct = 0; ct < 8; ++ct)
                    o[ct * 16] = acc[rt][ct][r];
            }
        }
    }
}

extern "C" void kernel_launch(void* const* d_in, const int* in_sizes, int n_in,
                              void* d_out, int out_size, void* d_ws, size_t ws_size,
                              hipStream_t stream) {
    const float* h      = (const float*)d_in[0];
    const int*   src    = (const int*)d_in[1];
    const int*   dst    = (const int*)d_in[2];
    const float* Wself  = (const float*)d_in[3];
    const float* Wneigh = (const float*)d_in[4];
    float*       out    = (float*)d_out;

    // workspace layout (~58 MB)
    unsigned short* hb = (unsigned short*)d_ws;            // NN*D bf16 (25.6MB)
    unsigned short* nb = hb + (size_t)NN * D;              // NN*D bf16 (25.6MB)
    unsigned short* Wp = nb + (size_t)NN * D;              // 256*128 bf16 (64KB)
    unsigned* packed   = (unsigned*)(Wp + 256 * D);        // NE (6.4MB)
    int* bcnt          = (int*)(packed + NE);              // NB
    int* bbase         = bcnt + NB;                        // NB+1
    int* bcursor       = bbase + NB + 1;                   // NB

    hipMemsetAsync(bcnt, 0, NB * sizeof(int), stream);

    k_cvt_h <<<dim3(NN * D / 8 / 256), 256, 0, stream>>>(h, hb);
    k_cvt_w <<<dim3(32), 128, 0, stream>>>(Wself, Wneigh, Wp);
    k_bhist <<<dim3(128), 256, 0, stream>>>(dst, bcnt);
    k_bscan <<<dim3(1), 256, 0, stream>>>(bcnt, bbase, bcursor);
    k_part  <<<dim3((NE + PB - 1) / PB), 256, 0, stream>>>(src, dst, bcursor, packed);
    k_agg   <<<dim3(NB), 256, 0, stream>>>(hb, bbase, packed, nb);
    k_gemm  <<<dim3((NN + 127) / 128), 256, 0, stream>>>(hb, nb, Wp, out);
}